// Round 15
// baseline (520.592 us; speedup 1.0000x reference)
//
#include <hip/hip_runtime.h>

#define NN 50000
#define EE 800000
#define INF 32
#define PEF 15
#define HID 128
#define GG 64
#define NLAYERS 4
#define NBLK 196    // ceil(NN/256)
#define NBUCK 49    // ceil(NN/1024)
#define ECH 4096    // edges per bin block
#define EBLK 196    // ceil(EE/ECH)

typedef __bf16 bf16;
typedef __attribute__((ext_vector_type(8))) bf16 bf16x8;
typedef __attribute__((ext_vector_type(4))) float f32x4;
typedef __attribute__((ext_vector_type(2))) float f32x2;

__device__ __forceinline__ float wave_allsum(float v) {
  #pragma unroll
  for (int off = 1; off < 64; off <<= 1) v += __shfl_xor(v, off);
  return v;
}

__device__ __forceinline__ float bflo(unsigned u) {
  return __builtin_bit_cast(float, u << 16);
}
__device__ __forceinline__ float bfhi(unsigned u) {
  return __builtin_bit_cast(float, u & 0xffff0000u);
}
__device__ __forceinline__ unsigned short f2bf(float v) {
  unsigned b = __builtin_bit_cast(unsigned, v);
  unsigned r = (b + 0x7fffu + ((b >> 16) & 1u)) >> 16;
  return (unsigned short)r;
}
__device__ __forceinline__ unsigned bfpack(float lo, float hi) {
  return (unsigned)f2bf(lo) | ((unsigned)f2bf(hi) << 16);
}
__device__ __forceinline__ unsigned fp8pack4(float a, float b, float c, float d) {
  unsigned lo = (unsigned)__builtin_amdgcn_cvt_pk_fp8_f32(a, b, 0, false) & 0xffffu;
  unsigned hi = (unsigned)__builtin_amdgcn_cvt_pk_fp8_f32(c, d, 0, false) & 0xffffu;
  return lo | (hi << 16);
}

// ---------------- merged weight packing ----------------
// region A [0, 65536): Wcatb (kv-cell-paired permutation):
//   o<128 q | o in [128,384): g=(o-128)>>6, c=(o-128)&63: c<32 -> k 32g+c else v 32g+c-32
//   | o>=384 skip.
// region B [65536, 73728): nwtb bf16 [128][64] (cols 47..63 zero)
// region C [73728, 90112): g1wb bf16 [128][128]
__global__ void pack_all_kernel(const float* __restrict__ Wq, const float* __restrict__ Wk,
                                const float* __restrict__ Wv, const float* __restrict__ Ws,
                                const float* __restrict__ bq, const float* __restrict__ bk,
                                const float* __restrict__ bv, const float* __restrict__ bs,
                                const float* __restrict__ niw, const float* __restrict__ g1w,
                                unsigned short* __restrict__ Wcatb, float* __restrict__ bcat,
                                unsigned short* __restrict__ nwtb, unsigned short* __restrict__ g1wb) {
  int idx = blockIdx.x * blockDim.x + threadIdx.x;
  if (idx < 512 * 128) {
    int o = idx >> 7, j = idx & 127;
    const float* W; const float* b; int r;
    if (o < 128) { W = Wq; b = bq; r = o; }
    else if (o < 384) {
      int g = (o - 128) >> 6, c = (o - 128) & 63;
      if (c < 32) { W = Wk; b = bk; r = 32 * g + c; }
      else        { W = Wv; b = bv; r = 32 * g + (c - 32); }
    } else { W = Ws; b = bs; r = o - 384; }
    Wcatb[idx] = f2bf(W[r * 128 + j]);
    if (j == 0) bcat[o] = b[r];
  } else if (idx < 512 * 128 + 128 * 64) {
    int k = idx - 512 * 128;
    int n = k >> 6, j = k & 63;
    nwtb[k] = (j < INF + PEF) ? f2bf(niw[n * (INF + PEF) + j]) : (unsigned short)0;
  } else if (idx < 512 * 128 + 128 * 64 + 128 * 128) {
    int k = idx - (512 * 128 + 128 * 64);
    g1wb[k] = f2bf(g1w[k]);
  }
}

// [x|pe] -> bf16 [N][64] padded
__global__ __launch_bounds__(256) void xpe_pack_kernel(const float* __restrict__ x,
    const float* __restrict__ pe, unsigned* __restrict__ xpeb4) {
  int n = blockIdx.x * 256 + threadIdx.x;
  if (n >= NN) return;
  unsigned ou[32];
  const float4* xr = (const float4*)(x + (size_t)n * INF);
  #pragma unroll
  for (int i = 0; i < 8; i++) {
    float4 v = xr[i];
    ou[2 * i] = bfpack(v.x, v.y);
    ou[2 * i + 1] = bfpack(v.z, v.w);
  }
  const float* pr = pe + (size_t)n * PEF;
  float p[16];
  #pragma unroll
  for (int i = 0; i < PEF; i++) p[i] = pr[i];
  p[15] = 0.f;
  #pragma unroll
  for (int i = 0; i < 8; i++) ou[16 + i] = bfpack(p[2 * i], p[2 * i + 1]);
  #pragma unroll
  for (int i = 24; i < 32; i++) ou[i] = 0u;
  unsigned* dst = xpeb4 + (size_t)n * 32;
  #pragma unroll
  for (int i = 0; i < 8; i++) ((uint4*)dst)[i] = *(uint4*)&ou[4 * i];
}

// ---------------- node_in MFMA GEMM: hbf = xpeb @ nwtb^T + nib (bf16 out) ------
__global__ __launch_bounds__(256) void nodein_gemm_kernel(
    const bf16* __restrict__ A, const bf16* __restrict__ B,
    const float* __restrict__ bias, int M, unsigned* __restrict__ hbf4) {
  __shared__ float lds[128 * 64];
  const int t = threadIdx.x;
  const int w = t >> 6, lane = t & 63;
  const int m0 = blockIdx.x * 128;
  const int n0 = blockIdx.y * 64;
  const int lrow = lane & 15, lk = (lane >> 4) * 8;
  int ra = m0 + w * 32 + lrow;      if (ra > M - 1) ra = M - 1;
  int rb = m0 + w * 32 + 16 + lrow; if (rb > M - 1) rb = M - 1;
  const bf16* a0p = A + (size_t)ra * 64 + lk;
  const bf16* a1p = A + (size_t)rb * 64 + lk;
  const bf16* bp  = B + (size_t)(n0 + lrow) * 64 + lk;
  f32x4 acc[2][4] = {};
  #pragma unroll
  for (int ks = 0; ks < 2; ks++) {
    bf16x8 a0 = *(const bf16x8*)(a0p + ks * 32);
    bf16x8 a1 = *(const bf16x8*)(a1p + ks * 32);
    #pragma unroll
    for (int nj = 0; nj < 4; nj++) {
      bf16x8 b = *(const bf16x8*)(bp + (size_t)nj * 1024 + ks * 32);
      acc[0][nj] = __builtin_amdgcn_mfma_f32_16x16x32_bf16(a0, b, acc[0][nj], 0, 0, 0);
      acc[1][nj] = __builtin_amdgcn_mfma_f32_16x16x32_bf16(a1, b, acc[1][nj], 0, 0, 0);
    }
  }
  const int rbase = (lane >> 4) * 4;
  #pragma unroll
  for (int mi = 0; mi < 2; mi++) {
    #pragma unroll
    for (int nj = 0; nj < 4; nj++) {
      #pragma unroll
      for (int r = 0; r < 4; r++) {
        int ml = w * 32 + mi * 16 + rbase + r;
        int col = nj * 16 + lrow;
        lds[ml * 64 + (col ^ ((ml & 7) << 2))] = acc[mi][nj][r] + bias[n0 + col];
      }
    }
  }
  __syncthreads();
  #pragma unroll
  for (int kk = 0; kk < 2; kk++) {
    int u = t + kk * 256;
    int r = u & 127, s = u >> 7;
    int m = m0 + r;
    if (m >= M) continue;
    float ff[16];
    #pragma unroll
    for (int j = 0; j < 4; j++) {
      int c = s * 16 + j * 4;
      *(float4*)(ff + j * 4) = *(const float4*)(lds + r * 64 + (c ^ ((r & 7) << 2)));
    }
    int c0 = n0 + s * 16;
    unsigned o[8];
    #pragma unroll
    for (int i = 0; i < 8; i++) o[i] = bfpack(ff[2 * i], ff[2 * i + 1]);
    uint4* hb = (uint4*)(hbf4 + (size_t)m * 64 + (c0 >> 1));
    hb[0] = *(uint4*)&o[0];
    hb[1] = *(uint4*)&o[4];
  }
}

// ---------------- CSR build: row_ptr ----------------
__global__ __launch_bounds__(256) void bsum_kernel(const int* __restrict__ counts,
                                                   int* __restrict__ bsum) {
  int b = blockIdx.x, t = threadIdx.x;
  int i = b * 256 + t;
  int v = (i < NN) ? counts[i] : 0;
  #pragma unroll
  for (int off = 1; off < 64; off <<= 1) v += __shfl_xor(v, off);
  __shared__ int red[4];
  if ((t & 63) == 0) red[t >> 6] = v;
  __syncthreads();
  if (t == 0) bsum[b] = red[0] + red[1] + red[2] + red[3];
}

__global__ void bscan_kernel(const int* __restrict__ bsum, int* __restrict__ bbase) {
  int lane = threadIdx.x;  // 64 threads, 1 block
  int carry = 0;
  for (int c = 0; c < NBLK; c += 64) {
    int i = c + lane;
    int v = (i < NBLK) ? bsum[i] : 0;
    int x = v;
    #pragma unroll
    for (int off = 1; off < 64; off <<= 1) {
      int u = __shfl_up(x, off);
      if (lane >= off) x += u;
    }
    if (i < NBLK) bbase[i] = carry + x - v;
    carry += __shfl(x, 63);
  }
}

__global__ __launch_bounds__(256) void rowptr_kernel(const int* __restrict__ counts,
    const int* __restrict__ bbase, int* __restrict__ row_ptr) {
  int b = blockIdx.x, t = threadIdx.x;
  int lane = t & 63, wid = t >> 6;
  int i = b * 256 + t;
  int v = (i < NN) ? counts[i] : 0;
  int x = v;
  #pragma unroll
  for (int off = 1; off < 64; off <<= 1) {
    int u = __shfl_up(x, off);
    if (lane >= off) x += u;
  }
  __shared__ int wsum[4];
  if (lane == 63) wsum[wid] = x;
  __syncthreads();
  int offs = bbase[b];
  for (int k = 0; k < wid; k++) offs += wsum[k];
  int incl = offs + x;
  if (i < NN) row_ptr[i + 1] = incl;
  if (b == 0 && t == 0) row_ptr[0] = 0;
}

// ---------------- binned scatter (XCD-local srcs writes) ----------------
__global__ __launch_bounds__(256) void binhist_kernel(const int* __restrict__ dst,
    int* __restrict__ blockHist, int* __restrict__ counts) {
  __shared__ int hist[NBUCK];
  int t = threadIdx.x;
  if (t < NBUCK) hist[t] = 0;
  __syncthreads();
  int base = blockIdx.x * ECH;
  int end = base + ECH; if (end > EE) end = EE;
  for (int i = base + t; i < end; i += 256) {
    int d = dst[i];
    atomicAdd(&hist[d >> 10], 1);
    atomicAdd(&counts[d], 1);
  }
  __syncthreads();
  if (t < NBUCK) blockHist[blockIdx.x * NBUCK + t] = hist[t];
}

__global__ void bscan2_kernel(const int* __restrict__ blockHist,
    int* __restrict__ blockBase, int* __restrict__ bucket_base) {
  int t = threadIdx.x;  // 64 threads, 1 block
  int tot = 0;
  if (t < NBUCK)
    for (int b = 0; b < EBLK; b++) tot += blockHist[b * NBUCK + t];
  int x = tot;
  #pragma unroll
  for (int off = 1; off < 64; off <<= 1) {
    int u = __shfl_up(x, off);
    if (t >= off) x += u;
  }
  int excl = x - tot;
  if (t < NBUCK) bucket_base[t] = excl;
  if (t == NBUCK - 1) bucket_base[NBUCK] = excl + tot;
  if (t < NBUCK) {
    int run = excl;
    for (int b = 0; b < EBLK; b++) {
      blockBase[b * NBUCK + t] = run;
      run += blockHist[b * NBUCK + t];
    }
  }
}

__global__ __launch_bounds__(256) void binwrite_kernel(const int* __restrict__ src,
    const int* __restrict__ dst, const int* __restrict__ blockBase,
    unsigned* __restrict__ binned) {
  __shared__ int cur[NBUCK];
  int t = threadIdx.x;
  if (t < NBUCK) cur[t] = blockBase[blockIdx.x * NBUCK + t];
  __syncthreads();
  int base = blockIdx.x * ECH;
  int end = base + ECH; if (end > EE) end = EE;
  for (int i = base + t; i < end; i += 256) {
    int d = dst[i];
    int p = atomicAdd(&cur[d >> 10], 1);
    binned[p] = (unsigned)src[i] | ((unsigned)(d & 1023) << 16);
  }
}

__global__ __launch_bounds__(512) void scatter2_kernel(const unsigned* __restrict__ binned,
    const int* __restrict__ row_ptr, const int* __restrict__ bucket_base,
    unsigned short* __restrict__ srcs16) {
  __shared__ int cur[1024];
  int g = blockIdx.x, t = threadIdx.x;
  int nbase = g << 10;
  for (int j = t; j < 1024; j += 512) {
    int node = nbase + j;
    cur[j] = (node < NN) ? row_ptr[node] : 0;
  }
  __syncthreads();
  int s0 = bucket_base[g], s1 = bucket_base[g + 1];
  for (int i = s0 + t; i < s1; i += 512) {
    unsigned pr = binned[i];
    int p = atomicAdd(&cur[pr >> 16], 1);
    srcs16[p] = (unsigned short)(pr & 0xffffu);
  }
}

__global__ void gptr_kernel(const int* __restrict__ batch, int* __restrict__ gptr) {
  int g = threadIdx.x;
  if (g > GG) return;
  if (g == GG) { gptr[GG] = NN; return; }
  int lo = 0, hi = NN;
  while (lo < hi) {
    int mid = (lo + hi) >> 1;
    if (batch[mid] < g) lo = mid + 1; else hi = mid;
  }
  gptr[g] = lo;
}

// ---------------- MFMA GEMM proj: [q bf16 | kv fp8 cells | xr bf16] ----------
// 1-D grid 3136, XCD-swizzled (verified r13: FETCH 50.5 -> 6.8 MB).
__global__ __launch_bounds__(256) void gemm0_kernel(
    const bf16* __restrict__ A, const bf16* __restrict__ B,
    const float* __restrict__ bias, int M,
    unsigned short* __restrict__ qbb, unsigned char* __restrict__ kvb,
    unsigned short* __restrict__ xrbb) {
  __shared__ float lds[128 * 64];  // 32 KB
  const int d = blockIdx.x;
  const int bx = (d >> 6) * 8 + (d & 7);
  const int by = (d >> 3) & 7;
  if (bx * 128 >= M) return;
  const int t = threadIdx.x;
  const int w = t >> 6, lane = t & 63;
  const int m0 = bx * 128;
  const int n0 = by * 64;
  const int lrow = lane & 15, lk = (lane >> 4) * 8;
  int ra = m0 + w * 32 + lrow;      if (ra > M - 1) ra = M - 1;
  int rb = m0 + w * 32 + 16 + lrow; if (rb > M - 1) rb = M - 1;
  const bf16* a0p = A + (size_t)ra * 128 + lk;
  const bf16* a1p = A + (size_t)rb * 128 + lk;
  const bf16* bp  = B + (size_t)(n0 + lrow) * 128 + lk;
  f32x4 acc[2][4] = {};
  #pragma unroll
  for (int ks = 0; ks < 4; ks++) {
    bf16x8 a0 = *(const bf16x8*)(a0p + ks * 32);
    bf16x8 a1 = *(const bf16x8*)(a1p + ks * 32);
    #pragma unroll
    for (int nj = 0; nj < 4; nj++) {
      bf16x8 b = *(const bf16x8*)(bp + (size_t)nj * 2048 + ks * 32);
      acc[0][nj] = __builtin_amdgcn_mfma_f32_16x16x32_bf16(a0, b, acc[0][nj], 0, 0, 0);
      acc[1][nj] = __builtin_amdgcn_mfma_f32_16x16x32_bf16(a1, b, acc[1][nj], 0, 0, 0);
    }
  }
  const int rbase = (lane >> 4) * 4;
  #pragma unroll
  for (int mi = 0; mi < 2; mi++) {
    #pragma unroll
    for (int nj = 0; nj < 4; nj++) {
      #pragma unroll
      for (int r = 0; r < 4; r++) {
        int ml = w * 32 + mi * 16 + rbase + r;
        int col = nj * 16 + lrow;
        lds[ml * 64 + (col ^ ((ml & 7) << 2))] = acc[mi][nj][r] + bias[n0 + col];
      }
    }
  }
  __syncthreads();
  if (by >= 2 && by < 6) {
    const int g = by - 2;
    #pragma unroll
    for (int kk = 0; kk < 2; kk++) {
      int u = t + kk * 256;
      int r = u >> 2, o = u & 3;
      int m = m0 + r;
      if (m >= M) continue;
      float fk[8], fv[8];
      int cK = o * 8, cV = 32 + o * 8;
      *(float4*)(fk)     = *(const float4*)(lds + r * 64 + ((cK)     ^ ((r & 7) << 2)));
      *(float4*)(fk + 4) = *(const float4*)(lds + r * 64 + ((cK + 4) ^ ((r & 7) << 2)));
      *(float4*)(fv)     = *(const float4*)(lds + r * 64 + ((cV)     ^ ((r & 7) << 2)));
      *(float4*)(fv + 4) = *(const float4*)(lds + r * 64 + ((cV + 4) ^ ((r & 7) << 2)));
      unsigned oc[4];
      oc[0] = fp8pack4(fk[0], fk[1], fk[2], fk[3]);
      oc[1] = fp8pack4(fk[4], fk[5], fk[6], fk[7]);
      oc[2] = fp8pack4(fv[0], fv[1], fv[2], fv[3]);
      oc[3] = fp8pack4(fv[4], fv[5], fv[6], fv[7]);
      *(uint4*)(kvb + (size_t)m * 256 + (size_t)(4 * g + o) * 16) = *(uint4*)oc;
    }
  } else {
    #pragma unroll
    for (int kk = 0; kk < 2; kk++) {
      int u = t + kk * 256;
      int r = u & 127, s = u >> 7;
      int m = m0 + r;
      if (m >= M) continue;
      float ff[16];
      #pragma unroll
      for (int j = 0; j < 4; j++) {
        int c = s * 16 + j * 4;
        *(float4*)(ff + j * 4) = *(const float4*)(lds + r * 64 + (c ^ ((r & 7) << 2)));
      }
      int c0 = (by & 1) * 64 + s * 16;
      unsigned o[8];
      #pragma unroll
      for (int i = 0; i < 8; i++) o[i] = bfpack(ff[2 * i], ff[2 * i + 1]);
      if (by < 2) {
        uint4* dq = (uint4*)(qbb + (size_t)m * 128 + c0);
        dq[0] = *(uint4*)&o[0];
        dq[1] = *(uint4*)&o[4];
      } else {
        uint4* dx = (uint4*)(xrbb + (size_t)m * 128 + c0);
        dx[0] = *(uint4*)&o[0];
        dx[1] = *(uint4*)&o[4];
      }
    }
  }
}

// ---------------- MFMA GEMM + fused gate ----
__global__ __launch_bounds__(512) void gemm1_gate_kernel(
    const bf16* __restrict__ A, const bf16* __restrict__ B,
    const float* __restrict__ b1, const float* __restrict__ g2w,
    const float* __restrict__ g2b, int M, float* __restrict__ gx) {
  const int w = threadIdx.x >> 6, lane = threadIdx.x & 63;
  const int m0 = blockIdx.x * 128 + w * 16;
  const int lrow = lane & 15, lk = (lane >> 4) * 8;
  int ra = m0 + lrow; if (ra > M - 1) ra = M - 1;
  const bf16* ap = A + (size_t)ra * 128 + lk;
  const bf16* bp = B + (size_t)lrow * 128 + lk;
  f32x4 acc[8] = {};
  #pragma unroll
  for (int ks = 0; ks < 4; ks++) {
    bf16x8 a = *(const bf16x8*)(ap + ks * 32);
    #pragma unroll
    for (int nj = 0; nj < 8; nj++) {
      bf16x8 b = *(const bf16x8*)(bp + (size_t)nj * 2048 + ks * 32);
      acc[nj] = __builtin_amdgcn_mfma_f32_16x16x32_bf16(a, b, acc[nj], 0, 0, 0);
    }
  }
  float g2v[8], b1v[8];
  #pragma unroll
  for (int nj = 0; nj < 8; nj++) {
    g2v[nj] = g2w[nj * 16 + lrow];
    b1v[nj] = b1[nj * 16 + lrow];
  }
  const float b2 = g2b[0];
  const int rbase = (lane >> 4) * 4;
  #pragma unroll
  for (int r = 0; r < 4; r++) {
    int m = m0 + rbase + r;
    float d = 0.f;
    #pragma unroll
    for (int nj = 0; nj < 8; nj++)
      d += fmaxf(acc[nj][r] + b1v[nj], 0.f) * g2v[nj];
    d += __shfl_xor(d, 1);
    d += __shfl_xor(d, 2);
    d += __shfl_xor(d, 4);
    d += __shfl_xor(d, 8);
    if (lrow == 0 && m < M) gx[m] = __expf(d + b2);
  }
}

// ---------------- fused edge attention + beta residual -------------------------
// Full-pair unpredicated main loop + short predicated tail; __expf intrinsic.
__global__ __launch_bounds__(256) void attn_beta_kernel(
    const unsigned short* __restrict__ qbb,  // [N][128] bf16
    const unsigned char* __restrict__ kvb,   // [N][256]B: 16 cells {k8|v8} fp8
    const int* __restrict__ row_ptr, const unsigned short* __restrict__ srcs,
    const unsigned* __restrict__ xrb4,       // [N][64] uint = [N][128] bf16
    const float* __restrict__ Wbeta,
    unsigned* __restrict__ hbf4) {
  __shared__ float xlds[4][128];
  const int wid = threadIdx.x >> 6;
  const int wv = blockIdx.x * 4 + wid;
  const int lane = threadIdx.x & 63;
  const int sl = lane & 15;
  const int eg = lane >> 4;
  float qf[8];
  {
    bf16x8 qv = *(const bf16x8*)((const bf16*)qbb + (size_t)wv * 128 + sl * 8);
    #pragma unroll
    for (int j = 0; j < 8; j++) qf[j] = (float)qv[j];
  }
  const int e0 = row_ptr[wv], e1 = row_ptr[wv + 1];
  const float SC = 0.17677669529663687f;  // 1/sqrt(32)
  const unsigned char* kvsl = kvb + sl * 16;
  float dex = 0.f;
  float acc[8] = {0, 0, 0, 0, 0, 0, 0, 0};

#define PBODY(cell, exexpr)                                                 \
  {                                                                         \
    f32x2 k0 = __builtin_amdgcn_cvt_pk_f32_fp8((cell).x, false);            \
    f32x2 k1 = __builtin_amdgcn_cvt_pk_f32_fp8((cell).x, true);             \
    f32x2 k2 = __builtin_amdgcn_cvt_pk_f32_fp8((cell).y, false);            \
    f32x2 k3 = __builtin_amdgcn_cvt_pk_f32_fp8((cell).y, true);             \
    float p = qf[0] * k0.x + qf[1] * k0.y + qf[2] * k1.x + qf[3] * k1.y     \
            + qf[4] * k2.x + qf[5] * k2.y + qf[6] * k3.x + qf[7] * k3.y;    \
    p += __shfl_xor(p, 1);                                                  \
    p += __shfl_xor(p, 2);                                                  \
    float ex = (exexpr);                                                    \
    dex += ex;                                                              \
    f32x2 v0 = __builtin_amdgcn_cvt_pk_f32_fp8((cell).z, false);            \
    f32x2 v1 = __builtin_amdgcn_cvt_pk_f32_fp8((cell).z, true);             \
    f32x2 v2 = __builtin_amdgcn_cvt_pk_f32_fp8((cell).w, false);            \
    f32x2 v3 = __builtin_amdgcn_cvt_pk_f32_fp8((cell).w, true);             \
    acc[0] += ex * v0.x; acc[1] += ex * v0.y;                               \
    acc[2] += ex * v1.x; acc[3] += ex * v1.y;                               \
    acc[4] += ex * v2.x; acc[5] += ex * v2.y;                               \
    acc[6] += ex * v3.x; acc[7] += ex * v3.y;                               \
  }
#define PROCF(cell) PBODY(cell, __expf(p * SC))
#define PROCT(cell, valid) PBODY(cell, (valid) ? __expf(p * SC) : 0.f)
#define LOADF(it, cvar)                                                     \
  {                                                                         \
    int s = (int)srcs[eBase + (it) * 4];                                    \
    cvar = *(const uint4*)(kvsl + (size_t)s * 256);                         \
  }

  const int eBase = e0 + eg;
  const int total = e1 - e0;
  const int nFull = total >> 3;   // full 8-edge pairs (all lanes valid)
  if (nFull > 0) {
    uint4 c0, c1;
    LOADF(0, c0);
    LOADF(1, c1);
    for (int p2 = 1; p2 < nFull; p2++) {
      uint4 n0, n1;
      LOADF(2 * p2, n0);
      LOADF(2 * p2 + 1, n1);
      PROCF(c0);
      PROCF(c1);
      c0 = n0; c1 = n1;
    }
    PROCF(c0);
    PROCF(c1);
  }
  {
    int base = nFull * 8;
    int rem = total - base;       // 0..7
    if (rem > 0) {
      bool v0 = eg < rem;
      int s0 = (int)srcs[e0 + base + (v0 ? eg : 0)];
      uint4 t0 = *(const uint4*)(kvsl + (size_t)s0 * 256);
      PROCT(t0, v0);
      if (rem > 4) {
        bool v1 = eg + 4 < rem;
        int s1 = (int)srcs[e0 + base + 4 + (v1 ? eg : 0)];
        uint4 t1 = *(const uint4*)(kvsl + (size_t)s1 * 256);
        PROCT(t1, v1);
      }
    }
  }
#undef PBODY
#undef PROCF
#undef PROCT
#undef LOADF

  // reduce across the 4 edge groups
  dex += __shfl_xor(dex, 16);
  dex += __shfl_xor(dex, 32);
  #pragma unroll
  for (int j = 0; j < 8; j++) {
    acc[j] += __shfl_xor(acc[j], 16);
    acc[j] += __shfl_xor(acc[j], 32);
  }
  float inv = (e1 > e0) ? 1.f / dex : 0.f;
  if (eg == 0) {
    #pragma unroll
    for (int j = 0; j < 8; j++) xlds[wid][sl * 8 + j] = acc[j] * inv;
  }
  __syncthreads();
  float ox = xlds[wid][2 * lane];
  float oy = xlds[wid][2 * lane + 1];
  // ---- beta gate + residual + relu (bf16 h state) ----
  unsigned xu = xrb4[(size_t)wv * 64 + lane];
  float xx = bflo(xu), xy = bfhi(xu);
  const float2* wb = (const float2*)Wbeta;
  float2 wo = wb[lane], wx = wb[64 + lane], wd = wb[128 + lane];
  float part = ox * wo.x + oy * wo.y + xx * wx.x + xy * wx.y
             + (ox - xx) * wd.x + (oy - xy) * wd.y;
  part = wave_allsum(part);
  float beta = 1.f / (1.f + __expf(-part));
  unsigned hu = hbf4[(size_t)wv * 64 + lane];
  float hx = bflo(hu), hy = bfhi(hu);
  float r0 = fmaxf(hx + beta * xx + (1.f - beta) * ox, 0.f);
  float r1 = fmaxf(hy + beta * xy + (1.f - beta) * oy, 0.f);
  hbf4[(size_t)wv * 64 + lane] = bfpack(r0, r1);
}

// ---------------- gate denominator / aggregation / readout ----------------
__global__ __launch_bounds__(256) void gden_kernel(const float* __restrict__ gx,
    const int* __restrict__ gptr, float* __restrict__ gden) {
  int g = blockIdx.x, t = threadIdx.x;
  int n0 = gptr[g], n1 = gptr[g + 1];
  float s = 0.f;
  for (int n = n0 + t; n < n1; n += 256) s += gx[n];
  s = wave_allsum(s);
  __shared__ float red[4];
  if ((t & 63) == 0) red[t >> 6] = s;
  __syncthreads();
  if (t == 0) gden[g] = red[0] + red[1] + red[2] + red[3];
}

__global__ __launch_bounds__(128) void gagg_kernel(const float* __restrict__ gx,
    const unsigned short* __restrict__ hbf, const int* __restrict__ gptr,
    float* __restrict__ gfeat_raw) {
  int g = blockIdx.x;
  int c = blockIdx.y;
  int d = threadIdx.x;
  int n0 = gptr[g], n1 = gptr[g + 1];
  float acc = 0.f;
  for (int n = n0 + c; n < n1; n += 32)
    acc += gx[n] * bflo((unsigned)hbf[(size_t)n * 128 + d]);
  atomicAdd(&gfeat_raw[g * 128 + d], acc);
}

__global__ __launch_bounds__(128) void readout_kernel(const float* __restrict__ gfeat_raw,
    const float* __restrict__ gden,
    const float* __restrict__ r1w, const float* __restrict__ r1b,
    const float* __restrict__ r2w, const float* __restrict__ r2b,
    float* __restrict__ out) {
  int g = blockIdx.x;
  int u = threadIdx.x;
  __shared__ float sh[128];
  __shared__ float red[128];
  float dv = gden[g];
  float inv = (dv > 0.f) ? 1.f / dv : 0.f;
  sh[u] = gfeat_raw[g * 128 + u] * inv;
  __syncthreads();
  float tacc = r1b[u];
  for (int j = 0; j < 128; j++) tacc += sh[j] * r1w[u * 128 + j];
  tacc = fmaxf(tacc, 0.f);
  red[u] = tacc * r2w[u];
  __syncthreads();
  for (int off = 64; off > 0; off >>= 1) {
    if (u < off) red[u] += red[u + off];
    __syncthreads();
  }
  if (u == 0) out[g] = red[0] + r2b[0];
}

extern "C" void kernel_launch(void* const* d_in, const int* in_sizes, int n_in,
                              void* d_out, int out_size, void* d_ws, size_t ws_size,
                              hipStream_t stream) {
  (void)in_sizes; (void)n_in; (void)out_size; (void)ws_size;
  const float* x     = (const float*)d_in[0];
  const int*   ei    = (const int*)d_in[1];
  const int*   batch = (const int*)d_in[2];
  const float* pe    = (const float*)d_in[3];
  const float* niw   = (const float*)d_in[4];
  const float* nib   = (const float*)d_in[5];
  const float* Wq    = (const float*)d_in[6];
  const float* bq    = (const float*)d_in[7];
  const float* Wk    = (const float*)d_in[8];
  const float* bk    = (const float*)d_in[9];
  const float* Wv    = (const float*)d_in[10];
  const float* bv    = (const float*)d_in[11];
  const float* Wsk   = (const float*)d_in[12];
  const float* bsk   = (const float*)d_in[13];
  const float* Wbeta = (const float*)d_in[14];
  const float* g1w   = (const float*)d_in[15];
  const float* g1b   = (const float*)d_in[16];
  const float* g2w   = (const float*)d_in[17];
  const float* g2b   = (const float*)d_in[18];
  const float* r1w   = (const float*)d_in[19];
  const float* r1b   = (const float*)d_in[20];
  const float* r2w   = (const float*)d_in[21];
  const float* r2b   = (const float*)d_in[22];
  float* out = (float*)d_out;

  float* ws = (float*)d_ws;
  float* qbbf  = ws; ws += (size_t)NN * 64;   // [N][128] bf16
  float* kvbf  = ws; ws += (size_t)NN * 64;   // [N][256] bytes fp8 cells
  float* xrbf  = ws; ws += (size_t)NN * 64;   // [N][128] bf16
  float* hbff  = ws; ws += (size_t)NN * 64;   // [N][128] bf16
  float* xpebf = ws; ws += (size_t)NN * 32;   // [N][64] bf16
  float* Wcatf = ws; ws += 512 * 64;
  float* g1wbf = ws; ws += 128 * 64;
  float* nwtbf = ws; ws += 128 * 32;          // [128][64] bf16
  float* bcat  = ws; ws += 512;
  float* gx    = ws; ws += NN;
  float* gfeat = ws; ws += GG * 128;
  float* gden  = ws; ws += GG;
  int* row_ptr = (int*)ws;
  int* counts   = row_ptr + (NN + 1);
  int* bsum     = counts + NN;
  int* bbase    = bsum + NBLK;
  int* gptr     = bbase + NBLK;
  int* blockHist= gptr + (GG + 1);
  int* blockBase= blockHist + EBLK * NBUCK;
  int* bucketB  = blockBase + EBLK * NBUCK;
  unsigned* binned = (unsigned*)(bucketB + (NBUCK + 1));
  unsigned short* srcs16 = (unsigned short*)(binned + EE);

  unsigned short* qbb   = (unsigned short*)qbbf;
  unsigned char*  kvb   = (unsigned char*)kvbf;
  unsigned short* xrbb  = (unsigned short*)xrbf;
  unsigned short* hbf   = (unsigned short*)hbff;
  unsigned short* Wcatb = (unsigned short*)Wcatf;
  unsigned short* g1wb  = (unsigned short*)g1wbf;
  unsigned short* nwtb  = (unsigned short*)nwtbf;
  const int* src = ei;
  const int* dst = ei + EE;

  hipMemsetAsync(counts, 0, NN * sizeof(int), stream);
  hipMemsetAsync(gfeat, 0, GG * 128 * sizeof(float), stream);
  pack_all_kernel<<<(512 * 128 + 128 * 64 + 128 * 128 + 255) / 256, 256, 0, stream>>>(
      Wq, Wk, Wv, Wsk, bq, bk, bv, bsk, niw, g1w, Wcatb, bcat, nwtb, g1wb);
  xpe_pack_kernel<<<NBLK, 256, 0, stream>>>(x, pe, (unsigned*)xpebf);
  binhist_kernel<<<EBLK, 256, 0, stream>>>(dst, blockHist, counts);
  bsum_kernel<<<NBLK, 256, 0, stream>>>(counts, bsum);
  bscan_kernel<<<1, 64, 0, stream>>>(bsum, bbase);
  rowptr_kernel<<<NBLK, 256, 0, stream>>>(counts, bbase, row_ptr);
  bscan2_kernel<<<1, 64, 0, stream>>>(blockHist, blockBase, bucketB);
  binwrite_kernel<<<EBLK, 256, 0, stream>>>(src, dst, blockBase, binned);
  scatter2_kernel<<<NBUCK, 512, 0, stream>>>(binned, row_ptr, bucketB, srcs16);
  gptr_kernel<<<1, 128, 0, stream>>>(batch, gptr);

  const int MB0 = (NN + 127) / 128;  // 391
  nodein_gemm_kernel<<<dim3(MB0, 2), 256, 0, stream>>>(
      (const bf16*)xpebf, (const bf16*)nwtb, nib, NN, (unsigned*)hbf);

  const int G0 = ((MB0 + 7) / 8) * 64;  // 3136 swizzled blocks
  for (int l = 0; l < NLAYERS; l++) {
    gemm0_kernel<<<G0, 256, 0, stream>>>(
        (const bf16*)hbf, (const bf16*)Wcatb, bcat, NN, qbb, kvb, xrbb);
    attn_beta_kernel<<<12500, 256, 0, stream>>>(
        qbb, kvb, row_ptr, srcs16, (const unsigned*)xrbb, Wbeta, (unsigned*)hbf);
  }

  gemm1_gate_kernel<<<MB0, 512, 0, stream>>>(
      (const bf16*)hbf, (const bf16*)g1wb, g1b, g2w, g2b, NN, gx);
  gden_kernel<<<GG, 256, 0, stream>>>(gx, gptr, gden);
  gagg_kernel<<<dim3(GG, 32), 128, 0, stream>>>(gx, hbf, gptr, gfeat);
  readout_kernel<<<GG, 128, 0, stream>>>(gfeat, gden, r1w, r1b, r2w, r2b, out);
}

// Round 16
// 504.629 us; speedup vs baseline: 1.0316x; 1.0316x over previous
//
#include <hip/hip_runtime.h>

#define NN 50000
#define EE 800000
#define INF 32
#define PEF 15
#define HID 128
#define GG 64
#define NLAYERS 4
#define NBLK 196    // ceil(NN/256)
#define NBUCK 49    // ceil(NN/1024)
#define ECH 4096    // edges per bin block
#define EBLK 196    // ceil(EE/ECH)

typedef __bf16 bf16;
typedef __attribute__((ext_vector_type(8))) bf16 bf16x8;
typedef __attribute__((ext_vector_type(4))) float f32x4;
typedef __attribute__((ext_vector_type(2))) float f32x2;

__device__ __forceinline__ float wave_allsum(float v) {
  #pragma unroll
  for (int off = 1; off < 64; off <<= 1) v += __shfl_xor(v, off);
  return v;
}

__device__ __forceinline__ float bflo(unsigned u) {
  return __builtin_bit_cast(float, u << 16);
}
__device__ __forceinline__ float bfhi(unsigned u) {
  return __builtin_bit_cast(float, u & 0xffff0000u);
}
__device__ __forceinline__ unsigned short f2bf(float v) {
  unsigned b = __builtin_bit_cast(unsigned, v);
  unsigned r = (b + 0x7fffu + ((b >> 16) & 1u)) >> 16;
  return (unsigned short)r;
}
__device__ __forceinline__ unsigned bfpack(float lo, float hi) {
  return (unsigned)f2bf(lo) | ((unsigned)f2bf(hi) << 16);
}
__device__ __forceinline__ unsigned fp8pack4(float a, float b, float c, float d) {
  unsigned lo = (unsigned)__builtin_amdgcn_cvt_pk_fp8_f32(a, b, 0, false) & 0xffffu;
  unsigned hi = (unsigned)__builtin_amdgcn_cvt_pk_fp8_f32(c, d, 0, false) & 0xffffu;
  return lo | (hi << 16);
}

// ---------------- merged weight packing ----------------
__global__ void pack_all_kernel(const float* __restrict__ Wq, const float* __restrict__ Wk,
                                const float* __restrict__ Wv, const float* __restrict__ Ws,
                                const float* __restrict__ bq, const float* __restrict__ bk,
                                const float* __restrict__ bv, const float* __restrict__ bs,
                                const float* __restrict__ niw, const float* __restrict__ g1w,
                                unsigned short* __restrict__ Wcatb, float* __restrict__ bcat,
                                unsigned short* __restrict__ nwtb, unsigned short* __restrict__ g1wb) {
  int idx = blockIdx.x * blockDim.x + threadIdx.x;
  if (idx < 512 * 128) {
    int o = idx >> 7, j = idx & 127;
    const float* W; const float* b; int r;
    if (o < 128) { W = Wq; b = bq; r = o; }
    else if (o < 384) {
      int g = (o - 128) >> 6, c = (o - 128) & 63;
      if (c < 32) { W = Wk; b = bk; r = 32 * g + c; }
      else        { W = Wv; b = bv; r = 32 * g + (c - 32); }
    } else { W = Ws; b = bs; r = o - 384; }
    Wcatb[idx] = f2bf(W[r * 128 + j]);
    if (j == 0) bcat[o] = b[r];
  } else if (idx < 512 * 128 + 128 * 64) {
    int k = idx - 512 * 128;
    int n = k >> 6, j = k & 63;
    nwtb[k] = (j < INF + PEF) ? f2bf(niw[n * (INF + PEF) + j]) : (unsigned short)0;
  } else if (idx < 512 * 128 + 128 * 64 + 128 * 128) {
    int k = idx - (512 * 128 + 128 * 64);
    g1wb[k] = f2bf(g1w[k]);
  }
}

// [x|pe] -> bf16 [N][64] padded
__global__ __launch_bounds__(256) void xpe_pack_kernel(const float* __restrict__ x,
    const float* __restrict__ pe, unsigned* __restrict__ xpeb4) {
  int n = blockIdx.x * 256 + threadIdx.x;
  if (n >= NN) return;
  unsigned ou[32];
  const float4* xr = (const float4*)(x + (size_t)n * INF);
  #pragma unroll
  for (int i = 0; i < 8; i++) {
    float4 v = xr[i];
    ou[2 * i] = bfpack(v.x, v.y);
    ou[2 * i + 1] = bfpack(v.z, v.w);
  }
  const float* pr = pe + (size_t)n * PEF;
  float p[16];
  #pragma unroll
  for (int i = 0; i < PEF; i++) p[i] = pr[i];
  p[15] = 0.f;
  #pragma unroll
  for (int i = 0; i < 8; i++) ou[16 + i] = bfpack(p[2 * i], p[2 * i + 1]);
  #pragma unroll
  for (int i = 24; i < 32; i++) ou[i] = 0u;
  unsigned* dst = xpeb4 + (size_t)n * 32;
  #pragma unroll
  for (int i = 0; i < 8; i++) ((uint4*)dst)[i] = *(uint4*)&ou[4 * i];
}

// ---------------- node_in MFMA GEMM: hbf = xpeb @ nwtb^T + nib (bf16 out) ------
__global__ __launch_bounds__(256) void nodein_gemm_kernel(
    const bf16* __restrict__ A, const bf16* __restrict__ B,
    const float* __restrict__ bias, int M, unsigned* __restrict__ hbf4) {
  __shared__ float lds[128 * 64];
  const int t = threadIdx.x;
  const int w = t >> 6, lane = t & 63;
  const int m0 = blockIdx.x * 128;
  const int n0 = blockIdx.y * 64;
  const int lrow = lane & 15, lk = (lane >> 4) * 8;
  int ra = m0 + w * 32 + lrow;      if (ra > M - 1) ra = M - 1;
  int rb = m0 + w * 32 + 16 + lrow; if (rb > M - 1) rb = M - 1;
  const bf16* a0p = A + (size_t)ra * 64 + lk;
  const bf16* a1p = A + (size_t)rb * 64 + lk;
  const bf16* bp  = B + (size_t)(n0 + lrow) * 64 + lk;
  f32x4 acc[2][4] = {};
  #pragma unroll
  for (int ks = 0; ks < 2; ks++) {
    bf16x8 a0 = *(const bf16x8*)(a0p + ks * 32);
    bf16x8 a1 = *(const bf16x8*)(a1p + ks * 32);
    #pragma unroll
    for (int nj = 0; nj < 4; nj++) {
      bf16x8 b = *(const bf16x8*)(bp + (size_t)nj * 1024 + ks * 32);
      acc[0][nj] = __builtin_amdgcn_mfma_f32_16x16x32_bf16(a0, b, acc[0][nj], 0, 0, 0);
      acc[1][nj] = __builtin_amdgcn_mfma_f32_16x16x32_bf16(a1, b, acc[1][nj], 0, 0, 0);
    }
  }
  const int rbase = (lane >> 4) * 4;
  #pragma unroll
  for (int mi = 0; mi < 2; mi++) {
    #pragma unroll
    for (int nj = 0; nj < 4; nj++) {
      #pragma unroll
      for (int r = 0; r < 4; r++) {
        int ml = w * 32 + mi * 16 + rbase + r;
        int col = nj * 16 + lrow;
        lds[ml * 64 + (col ^ ((ml & 7) << 2))] = acc[mi][nj][r] + bias[n0 + col];
      }
    }
  }
  __syncthreads();
  #pragma unroll
  for (int kk = 0; kk < 2; kk++) {
    int u = t + kk * 256;
    int r = u & 127, s = u >> 7;
    int m = m0 + r;
    if (m >= M) continue;
    float ff[16];
    #pragma unroll
    for (int j = 0; j < 4; j++) {
      int c = s * 16 + j * 4;
      *(float4*)(ff + j * 4) = *(const float4*)(lds + r * 64 + (c ^ ((r & 7) << 2)));
    }
    int c0 = n0 + s * 16;
    unsigned o[8];
    #pragma unroll
    for (int i = 0; i < 8; i++) o[i] = bfpack(ff[2 * i], ff[2 * i + 1]);
    uint4* hb = (uint4*)(hbf4 + (size_t)m * 64 + (c0 >> 1));
    hb[0] = *(uint4*)&o[0];
    hb[1] = *(uint4*)&o[4];
  }
}

// ---------------- CSR build: row_ptr ----------------
__global__ __launch_bounds__(256) void bsum_kernel(const int* __restrict__ counts,
                                                   int* __restrict__ bsum) {
  int b = blockIdx.x, t = threadIdx.x;
  int i = b * 256 + t;
  int v = (i < NN) ? counts[i] : 0;
  #pragma unroll
  for (int off = 1; off < 64; off <<= 1) v += __shfl_xor(v, off);
  __shared__ int red[4];
  if ((t & 63) == 0) red[t >> 6] = v;
  __syncthreads();
  if (t == 0) bsum[b] = red[0] + red[1] + red[2] + red[3];
}

__global__ void bscan_kernel(const int* __restrict__ bsum, int* __restrict__ bbase) {
  int lane = threadIdx.x;  // 64 threads, 1 block
  int carry = 0;
  for (int c = 0; c < NBLK; c += 64) {
    int i = c + lane;
    int v = (i < NBLK) ? bsum[i] : 0;
    int x = v;
    #pragma unroll
    for (int off = 1; off < 64; off <<= 1) {
      int u = __shfl_up(x, off);
      if (lane >= off) x += u;
    }
    if (i < NBLK) bbase[i] = carry + x - v;
    carry += __shfl(x, 63);
  }
}

__global__ __launch_bounds__(256) void rowptr_kernel(const int* __restrict__ counts,
    const int* __restrict__ bbase, int* __restrict__ row_ptr) {
  int b = blockIdx.x, t = threadIdx.x;
  int lane = t & 63, wid = t >> 6;
  int i = b * 256 + t;
  int v = (i < NN) ? counts[i] : 0;
  int x = v;
  #pragma unroll
  for (int off = 1; off < 64; off <<= 1) {
    int u = __shfl_up(x, off);
    if (lane >= off) x += u;
  }
  __shared__ int wsum[4];
  if (lane == 63) wsum[wid] = x;
  __syncthreads();
  int offs = bbase[b];
  for (int k = 0; k < wid; k++) offs += wsum[k];
  int incl = offs + x;
  if (i < NN) row_ptr[i + 1] = incl;
  if (b == 0 && t == 0) row_ptr[0] = 0;
}

// ---------------- binned scatter (XCD-local srcs writes) ----------------
__global__ __launch_bounds__(256) void binhist_kernel(const int* __restrict__ dst,
    int* __restrict__ blockHist, int* __restrict__ counts) {
  __shared__ int hist[NBUCK];
  int t = threadIdx.x;
  if (t < NBUCK) hist[t] = 0;
  __syncthreads();
  int base = blockIdx.x * ECH;
  int end = base + ECH; if (end > EE) end = EE;
  for (int i = base + t; i < end; i += 256) {
    int d = dst[i];
    atomicAdd(&hist[d >> 10], 1);
    atomicAdd(&counts[d], 1);
  }
  __syncthreads();
  if (t < NBUCK) blockHist[blockIdx.x * NBUCK + t] = hist[t];
}

__global__ void bscan2_kernel(const int* __restrict__ blockHist,
    int* __restrict__ blockBase, int* __restrict__ bucket_base) {
  int t = threadIdx.x;  // 64 threads, 1 block
  int tot = 0;
  if (t < NBUCK)
    for (int b = 0; b < EBLK; b++) tot += blockHist[b * NBUCK + t];
  int x = tot;
  #pragma unroll
  for (int off = 1; off < 64; off <<= 1) {
    int u = __shfl_up(x, off);
    if (t >= off) x += u;
  }
  int excl = x - tot;
  if (t < NBUCK) bucket_base[t] = excl;
  if (t == NBUCK - 1) bucket_base[NBUCK] = excl + tot;
  if (t < NBUCK) {
    int run = excl;
    for (int b = 0; b < EBLK; b++) {
      blockBase[b * NBUCK + t] = run;
      run += blockHist[b * NBUCK + t];
    }
  }
}

__global__ __launch_bounds__(256) void binwrite_kernel(const int* __restrict__ src,
    const int* __restrict__ dst, const int* __restrict__ blockBase,
    unsigned* __restrict__ binned) {
  __shared__ int cur[NBUCK];
  int t = threadIdx.x;
  if (t < NBUCK) cur[t] = blockBase[blockIdx.x * NBUCK + t];
  __syncthreads();
  int base = blockIdx.x * ECH;
  int end = base + ECH; if (end > EE) end = EE;
  for (int i = base + t; i < end; i += 256) {
    int d = dst[i];
    int p = atomicAdd(&cur[d >> 10], 1);
    binned[p] = (unsigned)src[i] | ((unsigned)(d & 1023) << 16);
  }
}

__global__ __launch_bounds__(512) void scatter2_kernel(const unsigned* __restrict__ binned,
    const int* __restrict__ row_ptr, const int* __restrict__ bucket_base,
    unsigned short* __restrict__ srcs16) {
  __shared__ int cur[1024];
  int g = blockIdx.x, t = threadIdx.x;
  int nbase = g << 10;
  for (int j = t; j < 1024; j += 512) {
    int node = nbase + j;
    cur[j] = (node < NN) ? row_ptr[node] : 0;
  }
  __syncthreads();
  int s0 = bucket_base[g], s1 = bucket_base[g + 1];
  for (int i = s0 + t; i < s1; i += 512) {
    unsigned pr = binned[i];
    int p = atomicAdd(&cur[pr >> 16], 1);
    srcs16[p] = (unsigned short)(pr & 0xffffu);
  }
}

__global__ void gptr_kernel(const int* __restrict__ batch, int* __restrict__ gptr) {
  int g = threadIdx.x;
  if (g > GG) return;
  if (g == GG) { gptr[GG] = NN; return; }
  int lo = 0, hi = NN;
  while (lo < hi) {
    int mid = (lo + hi) >> 1;
    if (batch[mid] < g) lo = mid + 1; else hi = mid;
  }
  gptr[g] = lo;
}

// ---------------- MFMA GEMM proj: [q bf16 | kv fp8 cells | xr bf16] ----------
// 1-D grid 3136, XCD-swizzled (verified r13: FETCH 50.5 -> 6.8 MB).
__global__ __launch_bounds__(256) void gemm0_kernel(
    const bf16* __restrict__ A, const bf16* __restrict__ B,
    const float* __restrict__ bias, int M,
    unsigned short* __restrict__ qbb, unsigned char* __restrict__ kvb,
    unsigned short* __restrict__ xrbb) {
  __shared__ float lds[128 * 64];  // 32 KB
  const int d = blockIdx.x;
  const int bx = (d >> 6) * 8 + (d & 7);
  const int by = (d >> 3) & 7;
  if (bx * 128 >= M) return;
  const int t = threadIdx.x;
  const int w = t >> 6, lane = t & 63;
  const int m0 = bx * 128;
  const int n0 = by * 64;
  const int lrow = lane & 15, lk = (lane >> 4) * 8;
  int ra = m0 + w * 32 + lrow;      if (ra > M - 1) ra = M - 1;
  int rb = m0 + w * 32 + 16 + lrow; if (rb > M - 1) rb = M - 1;
  const bf16* a0p = A + (size_t)ra * 128 + lk;
  const bf16* a1p = A + (size_t)rb * 128 + lk;
  const bf16* bp  = B + (size_t)(n0 + lrow) * 128 + lk;
  f32x4 acc[2][4] = {};
  #pragma unroll
  for (int ks = 0; ks < 4; ks++) {
    bf16x8 a0 = *(const bf16x8*)(a0p + ks * 32);
    bf16x8 a1 = *(const bf16x8*)(a1p + ks * 32);
    #pragma unroll
    for (int nj = 0; nj < 4; nj++) {
      bf16x8 b = *(const bf16x8*)(bp + (size_t)nj * 2048 + ks * 32);
      acc[0][nj] = __builtin_amdgcn_mfma_f32_16x16x32_bf16(a0, b, acc[0][nj], 0, 0, 0);
      acc[1][nj] = __builtin_amdgcn_mfma_f32_16x16x32_bf16(a1, b, acc[1][nj], 0, 0, 0);
    }
  }
  const int rbase = (lane >> 4) * 4;
  #pragma unroll
  for (int mi = 0; mi < 2; mi++) {
    #pragma unroll
    for (int nj = 0; nj < 4; nj++) {
      #pragma unroll
      for (int r = 0; r < 4; r++) {
        int ml = w * 32 + mi * 16 + rbase + r;
        int col = nj * 16 + lrow;
        lds[ml * 64 + (col ^ ((ml & 7) << 2))] = acc[mi][nj][r] + bias[n0 + col];
      }
    }
  }
  __syncthreads();
  if (by >= 2 && by < 6) {
    const int g = by - 2;
    #pragma unroll
    for (int kk = 0; kk < 2; kk++) {
      int u = t + kk * 256;
      int r = u >> 2, o = u & 3;
      int m = m0 + r;
      if (m >= M) continue;
      float fk[8], fv[8];
      int cK = o * 8, cV = 32 + o * 8;
      *(float4*)(fk)     = *(const float4*)(lds + r * 64 + ((cK)     ^ ((r & 7) << 2)));
      *(float4*)(fk + 4) = *(const float4*)(lds + r * 64 + ((cK + 4) ^ ((r & 7) << 2)));
      *(float4*)(fv)     = *(const float4*)(lds + r * 64 + ((cV)     ^ ((r & 7) << 2)));
      *(float4*)(fv + 4) = *(const float4*)(lds + r * 64 + ((cV + 4) ^ ((r & 7) << 2)));
      unsigned oc[4];
      oc[0] = fp8pack4(fk[0], fk[1], fk[2], fk[3]);
      oc[1] = fp8pack4(fk[4], fk[5], fk[6], fk[7]);
      oc[2] = fp8pack4(fv[0], fv[1], fv[2], fv[3]);
      oc[3] = fp8pack4(fv[4], fv[5], fv[6], fv[7]);
      *(uint4*)(kvb + (size_t)m * 256 + (size_t)(4 * g + o) * 16) = *(uint4*)oc;
    }
  } else {
    #pragma unroll
    for (int kk = 0; kk < 2; kk++) {
      int u = t + kk * 256;
      int r = u & 127, s = u >> 7;
      int m = m0 + r;
      if (m >= M) continue;
      float ff[16];
      #pragma unroll
      for (int j = 0; j < 4; j++) {
        int c = s * 16 + j * 4;
        *(float4*)(ff + j * 4) = *(const float4*)(lds + r * 64 + (c ^ ((r & 7) << 2)));
      }
      int c0 = (by & 1) * 64 + s * 16;
      unsigned o[8];
      #pragma unroll
      for (int i = 0; i < 8; i++) o[i] = bfpack(ff[2 * i], ff[2 * i + 1]);
      if (by < 2) {
        uint4* dq = (uint4*)(qbb + (size_t)m * 128 + c0);
        dq[0] = *(uint4*)&o[0];
        dq[1] = *(uint4*)&o[4];
      } else {
        uint4* dx = (uint4*)(xrbb + (size_t)m * 128 + c0);
        dx[0] = *(uint4*)&o[0];
        dx[1] = *(uint4*)&o[4];
      }
    }
  }
}

// ---------------- MFMA GEMM + fused gate ----
__global__ __launch_bounds__(512) void gemm1_gate_kernel(
    const bf16* __restrict__ A, const bf16* __restrict__ B,
    const float* __restrict__ b1, const float* __restrict__ g2w,
    const float* __restrict__ g2b, int M, float* __restrict__ gx) {
  const int w = threadIdx.x >> 6, lane = threadIdx.x & 63;
  const int m0 = blockIdx.x * 128 + w * 16;
  const int lrow = lane & 15, lk = (lane >> 4) * 8;
  int ra = m0 + lrow; if (ra > M - 1) ra = M - 1;
  const bf16* ap = A + (size_t)ra * 128 + lk;
  const bf16* bp = B + (size_t)lrow * 128 + lk;
  f32x4 acc[8] = {};
  #pragma unroll
  for (int ks = 0; ks < 4; ks++) {
    bf16x8 a = *(const bf16x8*)(ap + ks * 32);
    #pragma unroll
    for (int nj = 0; nj < 8; nj++) {
      bf16x8 b = *(const bf16x8*)(bp + (size_t)nj * 2048 + ks * 32);
      acc[nj] = __builtin_amdgcn_mfma_f32_16x16x32_bf16(a, b, acc[nj], 0, 0, 0);
    }
  }
  float g2v[8], b1v[8];
  #pragma unroll
  for (int nj = 0; nj < 8; nj++) {
    g2v[nj] = g2w[nj * 16 + lrow];
    b1v[nj] = b1[nj * 16 + lrow];
  }
  const float b2 = g2b[0];
  const int rbase = (lane >> 4) * 4;
  #pragma unroll
  for (int r = 0; r < 4; r++) {
    int m = m0 + rbase + r;
    float d = 0.f;
    #pragma unroll
    for (int nj = 0; nj < 8; nj++)
      d += fmaxf(acc[nj][r] + b1v[nj], 0.f) * g2v[nj];
    d += __shfl_xor(d, 1);
    d += __shfl_xor(d, 2);
    d += __shfl_xor(d, 4);
    d += __shfl_xor(d, 8);
    if (lrow == 0 && m < M) gx[m] = __expf(d + b2);
  }
}

// ---------------- fused edge attention + beta residual -------------------------
// Round-12 structure: direct srcs16 loads, depth-2 pipeline, exp2f. (36 VGPR)
__global__ __launch_bounds__(256) void attn_beta_kernel(
    const unsigned short* __restrict__ qbb,  // [N][128] bf16
    const unsigned char* __restrict__ kvb,   // [N][256]B: 16 cells {k8|v8} fp8
    const int* __restrict__ row_ptr, const unsigned short* __restrict__ srcs,
    const unsigned* __restrict__ xrb4,       // [N][64] uint = [N][128] bf16
    const float* __restrict__ Wbeta,
    unsigned* __restrict__ hbf4) {
  __shared__ float xlds[4][128];
  const int wid = threadIdx.x >> 6;
  const int wv = blockIdx.x * 4 + wid;
  const int lane = threadIdx.x & 63;
  const int sl = lane & 15;
  const int eg = lane >> 4;
  const int sl16 = sl * 16;
  float qf[8];
  {
    bf16x8 qv = *(const bf16x8*)((const bf16*)qbb + (size_t)wv * 128 + sl * 8);
    #pragma unroll
    for (int j = 0; j < 8; j++) qf[j] = (float)qv[j];
  }
  const int e0 = row_ptr[wv], e1 = row_ptr[wv + 1];
  const float C = 0.25503486f;  // (1/sqrt(32)) * log2(e)
  float dex = 0.f;
  float acc[8] = {0, 0, 0, 0, 0, 0, 0, 0};

#define PROC(cell, valid)                                                   \
  {                                                                         \
    f32x2 k0 = __builtin_amdgcn_cvt_pk_f32_fp8((cell).x, false);            \
    f32x2 k1 = __builtin_amdgcn_cvt_pk_f32_fp8((cell).x, true);             \
    f32x2 k2 = __builtin_amdgcn_cvt_pk_f32_fp8((cell).y, false);            \
    f32x2 k3 = __builtin_amdgcn_cvt_pk_f32_fp8((cell).y, true);             \
    float p = qf[0] * k0.x + qf[1] * k0.y + qf[2] * k1.x + qf[3] * k1.y     \
            + qf[4] * k2.x + qf[5] * k2.y + qf[6] * k3.x + qf[7] * k3.y;    \
    p += __shfl_xor(p, 1);                                                  \
    p += __shfl_xor(p, 2);                                                  \
    float ex = (valid) ? exp2f(p * C) : 0.f;                                \
    dex += ex;                                                              \
    f32x2 v0 = __builtin_amdgcn_cvt_pk_f32_fp8((cell).z, false);            \
    f32x2 v1 = __builtin_amdgcn_cvt_pk_f32_fp8((cell).z, true);             \
    f32x2 v2 = __builtin_amdgcn_cvt_pk_f32_fp8((cell).w, false);            \
    f32x2 v3 = __builtin_amdgcn_cvt_pk_f32_fp8((cell).w, true);             \
    acc[0] += ex * v0.x; acc[1] += ex * v0.y;                               \
    acc[2] += ex * v1.x; acc[3] += ex * v1.y;                               \
    acc[4] += ex * v2.x; acc[5] += ex * v2.y;                               \
    acc[6] += ex * v3.x; acc[7] += ex * v3.y;                               \
  }

#define LOADW(it, cvar, vvar)                                               \
  {                                                                         \
    int ei = eBase + (it) * 4;                                              \
    vvar = ei < e1;                                                         \
    int s = (int)srcs[vvar ? ei : e0];                                      \
    cvar = *(const uint4*)(kvb + (size_t)s * 256 + sl16);                   \
  }

  const int eBase = e0 + eg;
  const int nIt = (e1 - e0 + 3) >> 2;
  if (nIt > 0) {
    uint4 c0, c1; bool v0, v1;
    LOADW(0, c0, v0);
    LOADW(1, c1, v1);
    const int nPair = (nIt + 1) >> 1;
    for (int p2 = 1; p2 < nPair; p2++) {
      uint4 n0, n1; bool w0, w1;
      LOADW(2 * p2, n0, w0);
      LOADW(2 * p2 + 1, n1, w1);
      PROC(c0, v0);
      PROC(c1, v1);
      c0 = n0; v0 = w0; c1 = n1; v1 = w1;
    }
    PROC(c0, v0);
    PROC(c1, v1);
  }
#undef PROC
#undef LOADW

  // reduce across the 4 edge groups
  dex += __shfl_xor(dex, 16);
  dex += __shfl_xor(dex, 32);
  #pragma unroll
  for (int j = 0; j < 8; j++) {
    acc[j] += __shfl_xor(acc[j], 16);
    acc[j] += __shfl_xor(acc[j], 32);
  }
  float inv = (e1 > e0) ? 1.f / dex : 0.f;
  if (eg == 0) {
    #pragma unroll
    for (int j = 0; j < 8; j++) xlds[wid][sl * 8 + j] = acc[j] * inv;
  }
  __syncthreads();
  float ox = xlds[wid][2 * lane];
  float oy = xlds[wid][2 * lane + 1];
  // ---- beta gate + residual + relu (bf16 h state) ----
  unsigned xu = xrb4[(size_t)wv * 64 + lane];
  float xx = bflo(xu), xy = bfhi(xu);
  const float2* wb = (const float2*)Wbeta;
  float2 wo = wb[lane], wx = wb[64 + lane], wd = wb[128 + lane];
  float part = ox * wo.x + oy * wo.y + xx * wx.x + xy * wx.y
             + (ox - xx) * wd.x + (oy - xy) * wd.y;
  part = wave_allsum(part);
  float beta = 1.f / (1.f + __expf(-part));
  unsigned hu = hbf4[(size_t)wv * 64 + lane];
  float hx = bflo(hu), hy = bfhi(hu);
  float r0 = fmaxf(hx + beta * xx + (1.f - beta) * ox, 0.f);
  float r1 = fmaxf(hy + beta * xy + (1.f - beta) * oy, 0.f);
  hbf4[(size_t)wv * 64 + lane] = bfpack(r0, r1);
}

// ---------------- gate denominator / aggregation / readout ----------------
__global__ __launch_bounds__(256) void gden_kernel(const float* __restrict__ gx,
    const int* __restrict__ gptr, float* __restrict__ gden) {
  int g = blockIdx.x, t = threadIdx.x;
  int n0 = gptr[g], n1 = gptr[g + 1];
  float s = 0.f;
  for (int n = n0 + t; n < n1; n += 256) s += gx[n];
  s = wave_allsum(s);
  __shared__ float red[4];
  if ((t & 63) == 0) red[t >> 6] = s;
  __syncthreads();
  if (t == 0) gden[g] = red[0] + red[1] + red[2] + red[3];
}

__global__ __launch_bounds__(128) void gagg_kernel(const float* __restrict__ gx,
    const unsigned short* __restrict__ hbf, const int* __restrict__ gptr,
    float* __restrict__ gfeat_raw) {
  int g = blockIdx.x;
  int c = blockIdx.y;
  int d = threadIdx.x;
  int n0 = gptr[g], n1 = gptr[g + 1];
  float acc = 0.f;
  for (int n = n0 + c; n < n1; n += 32)
    acc += gx[n] * bflo((unsigned)hbf[(size_t)n * 128 + d]);
  atomicAdd(&gfeat_raw[g * 128 + d], acc);
}

__global__ __launch_bounds__(128) void readout_kernel(const float* __restrict__ gfeat_raw,
    const float* __restrict__ gden,
    const float* __restrict__ r1w, const float* __restrict__ r1b,
    const float* __restrict__ r2w, const float* __restrict__ r2b,
    float* __restrict__ out) {
  int g = blockIdx.x;
  int u = threadIdx.x;
  __shared__ float sh[128];
  __shared__ float red[128];
  float dv = gden[g];
  float inv = (dv > 0.f) ? 1.f / dv : 0.f;
  sh[u] = gfeat_raw[g * 128 + u] * inv;
  __syncthreads();
  float tacc = r1b[u];
  for (int j = 0; j < 128; j++) tacc += sh[j] * r1w[u * 128 + j];
  tacc = fmaxf(tacc, 0.f);
  red[u] = tacc * r2w[u];
  __syncthreads();
  for (int off = 64; off > 0; off >>= 1) {
    if (u < off) red[u] += red[u + off];
    __syncthreads();
  }
  if (u == 0) out[g] = red[0] + r2b[0];
}

extern "C" void kernel_launch(void* const* d_in, const int* in_sizes, int n_in,
                              void* d_out, int out_size, void* d_ws, size_t ws_size,
                              hipStream_t stream) {
  (void)in_sizes; (void)n_in; (void)out_size; (void)ws_size;
  const float* x     = (const float*)d_in[0];
  const int*   ei    = (const int*)d_in[1];
  const int*   batch = (const int*)d_in[2];
  const float* pe    = (const float*)d_in[3];
  const float* niw   = (const float*)d_in[4];
  const float* nib   = (const float*)d_in[5];
  const float* Wq    = (const float*)d_in[6];
  const float* bq    = (const float*)d_in[7];
  const float* Wk    = (const float*)d_in[8];
  const float* bk    = (const float*)d_in[9];
  const float* Wv    = (const float*)d_in[10];
  const float* bv    = (const float*)d_in[11];
  const float* Wsk   = (const float*)d_in[12];
  const float* bsk   = (const float*)d_in[13];
  const float* Wbeta = (const float*)d_in[14];
  const float* g1w   = (const float*)d_in[15];
  const float* g1b   = (const float*)d_in[16];
  const float* g2w   = (const float*)d_in[17];
  const float* g2b   = (const float*)d_in[18];
  const float* r1w   = (const float*)d_in[19];
  const float* r1b   = (const float*)d_in[20];
  const float* r2w   = (const float*)d_in[21];
  const float* r2b   = (const float*)d_in[22];
  float* out = (float*)d_out;

  float* ws = (float*)d_ws;
  float* qbbf  = ws; ws += (size_t)NN * 64;   // [N][128] bf16
  float* kvbf  = ws; ws += (size_t)NN * 64;   // [N][256] bytes fp8 cells
  float* xrbf  = ws; ws += (size_t)NN * 64;   // [N][128] bf16
  float* hbff  = ws; ws += (size_t)NN * 64;   // [N][128] bf16
  float* xpebf = ws; ws += (size_t)NN * 32;   // [N][64] bf16
  float* Wcatf = ws; ws += 512 * 64;
  float* g1wbf = ws; ws += 128 * 64;
  float* nwtbf = ws; ws += 128 * 32;          // [128][64] bf16
  float* bcat  = ws; ws += 512;
  float* gx    = ws; ws += NN;
  float* gfeat = ws; ws += GG * 128;
  float* gden  = ws; ws += GG;
  int* row_ptr = (int*)ws;
  int* counts   = row_ptr + (NN + 1);
  int* bsum     = counts + NN;
  int* bbase    = bsum + NBLK;
  int* gptr     = bbase + NBLK;
  int* blockHist= gptr + (GG + 1);
  int* blockBase= blockHist + EBLK * NBUCK;
  int* bucketB  = blockBase + EBLK * NBUCK;
  unsigned* binned = (unsigned*)(bucketB + (NBUCK + 1));
  unsigned short* srcs16 = (unsigned short*)(binned + EE);

  unsigned short* qbb   = (unsigned short*)qbbf;
  unsigned char*  kvb   = (unsigned char*)kvbf;
  unsigned short* xrbb  = (unsigned short*)xrbf;
  unsigned short* hbf   = (unsigned short*)hbff;
  unsigned short* Wcatb = (unsigned short*)Wcatf;
  unsigned short* g1wb  = (unsigned short*)g1wbf;
  unsigned short* nwtb  = (unsigned short*)nwtbf;
  const int* src = ei;
  const int* dst = ei + EE;

  hipMemsetAsync(counts, 0, NN * sizeof(int), stream);
  hipMemsetAsync(gfeat, 0, GG * 128 * sizeof(float), stream);
  pack_all_kernel<<<(512 * 128 + 128 * 64 + 128 * 128 + 255) / 256, 256, 0, stream>>>(
      Wq, Wk, Wv, Wsk, bq, bk, bv, bsk, niw, g1w, Wcatb, bcat, nwtb, g1wb);
  xpe_pack_kernel<<<NBLK, 256, 0, stream>>>(x, pe, (unsigned*)xpebf);
  binhist_kernel<<<EBLK, 256, 0, stream>>>(dst, blockHist, counts);
  bsum_kernel<<<NBLK, 256, 0, stream>>>(counts, bsum);
  bscan_kernel<<<1, 64, 0, stream>>>(bsum, bbase);
  rowptr_kernel<<<NBLK, 256, 0, stream>>>(counts, bbase, row_ptr);
  bscan2_kernel<<<1, 64, 0, stream>>>(blockHist, blockBase, bucketB);
  binwrite_kernel<<<EBLK, 256, 0, stream>>>(src, dst, blockBase, binned);
  scatter2_kernel<<<NBUCK, 512, 0, stream>>>(binned, row_ptr, bucketB, srcs16);
  gptr_kernel<<<1, 128, 0, stream>>>(batch, gptr);

  const int MB0 = (NN + 127) / 128;  // 391
  nodein_gemm_kernel<<<dim3(MB0, 2), 256, 0, stream>>>(
      (const bf16*)xpebf, (const bf16*)nwtb, nib, NN, (unsigned*)hbf);

  const int G0 = ((MB0 + 7) / 8) * 64;  // 3136 swizzled blocks
  for (int l = 0; l < NLAYERS; l++) {
    gemm0_kernel<<<G0, 256, 0, stream>>>(
        (const bf16*)hbf, (const bf16*)Wcatb, bcat, NN, qbb, kvb, xrbb);
    attn_beta_kernel<<<12500, 256, 0, stream>>>(
        qbb, kvb, row_ptr, srcs16, (const unsigned*)xrbb, Wbeta, (unsigned*)hbf);
  }

  gemm1_gate_kernel<<<MB0, 512, 0, stream>>>(
      (const bf16*)hbf, (const bf16*)g1wb, g1b, g2w, g2b, NN, gx);
  gden_kernel<<<GG, 256, 0, stream>>>(gx, gptr, gden);
  gagg_kernel<<<dim3(GG, 32), 128, 0, stream>>>(gx, hbf, gptr, gfeat);
  readout_kernel<<<GG, 128, 0, stream>>>(gfeat, gden, r1w, r1b, r2w, r2b, out);
}